// Round 8
// baseline (424.755 us; speedup 1.0000x reference)
//
#include <hip/hip_runtime.h>
#include <hip/hip_bf16.h>
#include <cstdint>
#include <cstddef>

// B=4, S=2048, H=16, hd=128, D=2048, 3D=6144
constexpr int CS = 2048;
constexpr int CHD = 128;
constexpr int CD = 2048;
constexpr int CN3 = 6144;

typedef __attribute__((ext_vector_type(8))) short short8;
typedef __attribute__((ext_vector_type(4))) float f32x4;
typedef __attribute__((ext_vector_type(4))) int int4v;

#define GLOAD_LDS16(g, l) __builtin_amdgcn_global_load_lds( \
    (const __attribute__((address_space(1))) void*)(g),      \
    (__attribute__((address_space(3))) void*)(l), 16, 0, 0)

__device__ __forceinline__ unsigned short f2bf(float f) {
  union { float f; unsigned u; } v; v.f = f;
  unsigned r = v.u + 0x7fffu + ((v.u >> 16) & 1u);
  return (unsigned short)(r >> 16);
}
// pack two f32 -> dword of 2x bf16 (lo=a, hi=b) using the same RNE bit-math
__device__ __forceinline__ unsigned pkbf(float a, float b) {
  return (unsigned)f2bf(a) | ((unsigned)f2bf(b) << 16);
}

// lane^1 value (quad_perm [1,0,3,2]) -- used by GEMM1 RoPE epilogue
__device__ __forceinline__ float dpp_xor1(float x) {
  return __builtin_bit_cast(float, __builtin_amdgcn_update_dpp(
      __builtin_bit_cast(int, x), __builtin_bit_cast(int, x), 0xB1, 0xf, 0xf, true));
}

// ---------- f32 -> bf16 elementwise ----------
__global__ __launch_bounds__(256) void k_cvt(const float* __restrict__ in,
                                             unsigned short* __restrict__ out, int n) {
  int i = (blockIdx.x * 256 + threadIdx.x) * 8;
  if (i >= n) return;
  float4 a = *(const float4*)(in + i);
  float4 b = *(const float4*)(in + i + 4);
  short8 o;
  o[0] = (short)f2bf(a.x); o[1] = (short)f2bf(a.y);
  o[2] = (short)f2bf(a.z); o[3] = (short)f2bf(a.w);
  o[4] = (short)f2bf(b.x); o[5] = (short)f2bf(b.y);
  o[6] = (short)f2bf(b.z); o[7] = (short)f2bf(b.w);
  *(short8*)(out + i) = o;
}

// ---------- transpose + convert: in [R][C] f32 -> out [C][R] bf16 ----------
__global__ __launch_bounds__(256) void k_transcvt(const float* __restrict__ in,
                                                  unsigned short* __restrict__ out,
                                                  int R, int C) {
  __shared__ float tile[32][33];
  int c0 = blockIdx.x * 32, r0 = blockIdx.y * 32;
  int tx = threadIdx.x & 31, ty = threadIdx.x >> 5;  // 32 x 8
#pragma unroll
  for (int j = 0; j < 4; ++j)
    tile[ty + 8 * j][tx] = in[(size_t)(r0 + ty + 8 * j) * C + c0 + tx];
  __syncthreads();
#pragma unroll
  for (int j = 0; j < 4; ++j)
    out[(size_t)(c0 + ty + 8 * j) * R + r0 + tx] = f2bf(tile[tx][ty + 8 * j]);
}

// ---------- RoPE cos/sin table [2048][64] float2 ----------
__global__ void k_ropetab(float2* __restrict__ tab) {
  int p = blockIdx.x, c = threadIdx.x;  // 64 threads
  float inv = powf(10000.0f, -(float)(2 * c) / 128.0f);
  float a = (float)p * inv;
  tab[p * 64 + c] = make_float2(cosf(a), sinf(a));
}

// ---------- GEMM1: 256x256 tile, BK=32, 64KB LDS -> 2 blocks/CU ----------
// R14: the R6/R8/R11 schedule failures were all at 1 block/CU (128KB LDS);
// no reordering can fill the barrier drain when nothing else is resident.
// BK=32 halves LDS to 64KB so 2 blocks co-reside and drains overlap (m114).
// Layout: rows of 64B; swizzle slot ^= (row>>1)&3 applied on the GLOBAL src
// (global_load_lds dest must be linear) and on fragment reads; b128 reads
// land exactly 8 accesses/bank = conflict-free. Counted-vmcnt dbuf: 4 stage
// calls/K-tile spread P0-P2 + post-barrier A-j0 prefetch, vmcnt(1) mid-loop.
// Epilogue: RoPE(q,k)+q-scale; V transposed to Vt via 64KB LDS in 2 s-halves.
__global__ __launch_bounds__(512, 2) void k_gemm32(
    const unsigned short* __restrict__ A,
    const unsigned short* __restrict__ Bt,
    unsigned short* __restrict__ outQ,
    unsigned short* __restrict__ outK,
    unsigned short* __restrict__ outV,
    const int* __restrict__ positions,
    const float2* __restrict__ tab,
    int K, int nbn) {
  const int nwg = gridDim.x;
  const int cpx = nwg >> 3;
  const int wg = blockIdx.x;
  const int swz = (wg & 7) * cpx + (wg >> 3);
  const int bn = swz % nbn, bm = swz / nbn;

  const int t = threadIdx.x;
  const int w = t >> 6, lane = t & 63;
  const int wr = w >> 2, wc = w & 3;       // 2 x 4 wave grid
  const int lr = lane & 15, lg = lane >> 4;

  __shared__ char L[65536];  // [buf:32K][A:16K | B:16K], rows of 64B

  const size_t Kb = (size_t)K * 2;
  const int srow = t >> 2;                                   // 0..127
  const int sslot = ((t & 3) ^ ((t >> 3) & 3)) * 16;         // pre-swizzled src
  const char* gA = (const char*)A + (size_t)(bm * 256 + srow) * Kb + sslot;
  const char* gB = (const char*)Bt + (size_t)(bn * 256 + srow) * Kb + sslot;

#define STG(BUFB, OP, J, KT)                                                   \
  GLOAD_LDS16(((OP) ? gB : gA) + (size_t)((J) * 128) * Kb + (size_t)(KT) * 64, \
              L + (BUFB) + (OP) * 16384 + (J) * 8192 + t * 16)

  const int xo2 = (lr >> 1) & 3;
  const int aR = (wr * 128 + lr) * 64;
  const int bR = (wc * 64 + lr) * 64;
#define RA(BUFB, MI) (*(const short8*)(L + (BUFB) + aR + (MI) * 1024 + ((lg ^ xo2) << 4)))
#define RB(BUFB, NI) (*(const short8*)(L + (BUFB) + 16384 + bR + (NI) * 1024 + ((lg ^ xo2) << 4)))

  f32x4 acc[8][4] = {};
  const int ktiles = K >> 5;

  // prologue: buf0 full (4), buf1 A-j0 (1); wait buf0
  STG(0, 0, 0, 0); STG(0, 0, 1, 0); STG(0, 1, 0, 0); STG(0, 1, 1, 0);
  STG(32768, 0, 0, 1);
  asm volatile("s_waitcnt vmcnt(1)" ::: "memory");
  __builtin_amdgcn_s_barrier();

  short8 af[4], bf[4];
  int c = 0;
  for (int kt = 0; kt < ktiles - 1; ++kt) {
    const int cb = c << 15, nb = (c ^ 1) << 15;
    // P0: read A0-3, B0-1; stage nb A-j1
#pragma unroll
    for (int mi = 0; mi < 4; ++mi) af[mi] = RA(cb, mi);
#pragma unroll
    for (int ni = 0; ni < 2; ++ni) bf[ni] = RB(cb, ni);
    STG(nb, 0, 1, kt + 1);
    __builtin_amdgcn_s_setprio(1);
#pragma unroll
    for (int mi = 0; mi < 4; ++mi)
#pragma unroll
      for (int ni = 0; ni < 2; ++ni)
        acc[mi][ni] = __builtin_amdgcn_mfma_f32_16x16x32_bf16(af[mi], bf[ni], acc[mi][ni], 0, 0, 0);
    __builtin_amdgcn_s_setprio(0);
    // P1: read B2-3; stage nb B-j0
#pragma unroll
    for (int ni = 2; ni < 4; ++ni) bf[ni] = RB(cb, ni);
    STG(nb, 1, 0, kt + 1);
    __builtin_amdgcn_s_setprio(1);
#pragma unroll
    for (int mi = 0; mi < 4; ++mi)
#pragma unroll
      for (int ni = 2; ni < 4; ++ni)
        acc[mi][ni] = __builtin_amdgcn_mfma_f32_16x16x32_bf16(af[mi], bf[ni], acc[mi][ni], 0, 0, 0);
    __builtin_amdgcn_s_setprio(0);
    // P2: read A4-7; stage nb B-j1
#pragma unroll
    for (int mi = 0; mi < 4; ++mi) af[mi] = RA(cb, mi + 4);
    STG(nb, 1, 1, kt + 1);
    __builtin_amdgcn_s_setprio(1);
#pragma unroll
    for (int mi = 0; mi < 4; ++mi)
#pragma unroll
      for (int ni = 2; ni < 4; ++ni)
        acc[mi + 4][ni] = __builtin_amdgcn_mfma_f32_16x16x32_bf16(af[mi], bf[ni], acc[mi + 4][ni], 0, 0, 0);
    __builtin_amdgcn_s_setprio(0);
    // P3
    __builtin_amdgcn_s_setprio(1);
#pragma unroll
    for (int mi = 0; mi < 4; ++mi)
#pragma unroll
      for (int ni = 0; ni < 2; ++ni)
        acc[mi + 4][ni] = __builtin_amdgcn_mfma_f32_16x16x32_bf16(af[mi], bf[ni], acc[mi + 4][ni], 0, 0, 0);
    __builtin_amdgcn_s_setprio(0);

    __builtin_amdgcn_s_barrier();   // all waves done reading cb
    if (kt + 2 < ktiles) {
      STG(cb, 0, 0, kt + 2);        // next-next A-j0 into freed cb
      asm volatile("s_waitcnt vmcnt(1)" ::: "memory");  // nb fully landed
    } else {
      asm volatile("s_waitcnt vmcnt(0)" ::: "memory");
    }
    __builtin_amdgcn_s_barrier();
    c ^= 1;
  }
  // tail K-tile: loose, reads only
  {
    const int cb = c << 15;
#pragma unroll
    for (int mi = 0; mi < 4; ++mi) af[mi] = RA(cb, mi);
#pragma unroll
    for (int ni = 0; ni < 2; ++ni) bf[ni] = RB(cb, ni);
    __builtin_amdgcn_s_setprio(1);
#pragma unroll
    for (int mi = 0; mi < 4; ++mi)
#pragma unroll
      for (int ni = 0; ni < 2; ++ni)
        acc[mi][ni] = __builtin_amdgcn_mfma_f32_16x16x32_bf16(af[mi], bf[ni], acc[mi][ni], 0, 0, 0);
    __builtin_amdgcn_s_setprio(0);
#pragma unroll
    for (int ni = 2; ni < 4; ++ni) bf[ni] = RB(cb, ni);
    __builtin_amdgcn_s_setprio(1);
#pragma unroll
    for (int mi = 0; mi < 4; ++mi)
#pragma unroll
      for (int ni = 2; ni < 4; ++ni)
        acc[mi][ni] = __builtin_amdgcn_mfma_f32_16x16x32_bf16(af[mi], bf[ni], acc[mi][ni], 0, 0, 0);
    __builtin_amdgcn_s_setprio(0);
#pragma unroll
    for (int mi = 0; mi < 4; ++mi) af[mi] = RA(cb, mi + 4);
    __builtin_amdgcn_s_setprio(1);
#pragma unroll
    for (int mi = 0; mi < 4; ++mi)
#pragma unroll
      for (int ni = 0; ni < 4; ++ni)
        acc[mi + 4][ni] = __builtin_amdgcn_mfma_f32_16x16x32_bf16(af[mi], bf[ni], acc[mi + 4][ni], 0, 0, 0);
    __builtin_amdgcn_s_setprio(0);
  }
#undef STG
#undef RA
#undef RB

  const int which = bn >> 3;  // 0=q 1=k 2=v
  if (which < 2) {
    const float qsc = which ? 1.0f : 0.08838834764831845f;  // 1/sqrt(128) for q
    unsigned short* dstB = which ? outK : outQ;
#pragma unroll
    for (int mi = 0; mi < 8; ++mi)
#pragma unroll
      for (int rr = 0; rr < 4; ++rr) {
        int mg = bm * 256 + wr * 128 + mi * 16 + lg * 4 + rr;
        int bb = mg >> 11, s = mg & 2047;
        int pos = positions[s];
        int srow2 = which ? pos : s;  // k goes to cache row positions[s]
        const float2* tb = tab + pos * 64 + wc * 32 + (lr >> 1);
#pragma unroll
        for (int ni = 0; ni < 4; ++ni) {
          int cn = bn * 256 + wc * 64 + ni * 16 + lr;
          int h = (cn >> 7) & 15, d = cn & 127;
          float x = acc[mi][ni][rr];
          float p = dpp_xor1(x);          // partner element of the rope pair
          float2 cs = tb[ni * 8];         // tab[pos][d>>1]
          float y = (lr & 1) ? (x * cs.x + p * cs.y)    // odd: x1*c + x0*s
                             : (x * cs.x - p * cs.y);   // even: x0*c - x1*s
          dstB[((size_t)(bb * 16 + h) * CS + srow2) * CHD + d] = f2bf(y * qsc);
        }
      }
  } else {
    // v: transpose 256x256 tile through 64KB LDS in 2 s-halves -> Vt [bh][d][s]
    unsigned short* TL = (unsigned short*)L;  // 256 x 128 bf16 = 64KB per pass
    const int bb = bm >> 3, s0 = (bm & 7) * 256;
    const int h0 = bn * 2 - 32;              // bn in [16,24)
    const int vcr = t >> 1, hs = t & 1;
    unsigned short* vrow = outV +
        ((size_t)((bb * 16 + h0 + (vcr >> 7)) * 128 + (vcr & 127))) * CS + s0;
#pragma unroll
    for (int hh = 0; hh < 2; ++hh) {
      __syncthreads();  // pass-0: K-loop reads done; pass-1: pass-0 reads done
      if (wr == hh) {
#pragma unroll
        for (int mi = 0; mi < 8; ++mi) {
          int sb = mi * 16 + lg * 4;  // s within half, 0..127
#pragma unroll
          for (int ni = 0; ni < 4; ++ni) {
            int vc = wc * 64 + ni * 16 + lr;
            unsigned lo = pkbf(acc[mi][ni][0], acc[mi][ni][1]);
            unsigned hi2 = pkbf(acc[mi][ni][2], acc[mi][ni][3]);
            unsigned long long v8 = (unsigned long long)lo | ((unsigned long long)hi2 << 32);
            *(unsigned long long*)(TL + vc * 128 + (sb ^ ((vc & 7) << 3))) = v8;
          }
        }
      }
      __syncthreads();
#pragma unroll
      for (int j = 0; j < 8; ++j) {
        short8 v = *(const short8*)(TL + vcr * 128 + ((hs * 64 + j * 8) ^ ((vcr & 7) << 3)));
        *(short8*)(vrow + hh * 128 + hs * 64 + j * 8) = v;
      }
    }
  }
}

// ---------- GEMM2: 256x256-tile BK=64 bf16 MFMA GEMM (R3-verified loose) ----------
template <int EPI>
__global__ __launch_bounds__(512, 2) void k_gemm256(
    const unsigned short* __restrict__ A,
    const unsigned short* __restrict__ Bt,
    float* __restrict__ outF,
    int M, int N, int K, int nbn) {
  const int nwg = gridDim.x;
  const int cpx = nwg >> 3;
  const int wg = blockIdx.x;
  const int swz = (wg & 7) * cpx + (wg >> 3);
  const int bn = swz % nbn, bm = swz / nbn;

  const int t = threadIdx.x;
  const int w = t >> 6, lane = t & 63;
  const int wr = w >> 2, wc = w & 3;       // 2 x 4 wave grid
  const int lr = lane & 15, lg = lane >> 4;

  __shared__ char L[131072];  // [buf:64K][op:32K = 256 rows x 128B]

  const size_t Kb = (size_t)K * 2;
  const int srl = w * 16 + (lane >> 3);
  const int sch = ((lane & 7) ^ (lane >> 3)) * 16;
  const char* gA = (const char*)A + (size_t)(bm * 256 + srl) * Kb + sch;
  const char* gB = (const char*)Bt + (size_t)(bn * 256 + srl) * Kb + sch;
  const int ldst = w * 2048 + lane * 16;

#define STAGE(BUFB, OP, HALF, J, KT)                                               \
  GLOAD_LDS16(((OP) ? gB : gA) + (size_t)((HALF) * 128 + (J) * 8) * Kb +           \
                  (size_t)(KT) * 128,                                              \
              L + (BUFB) + (OP) * 32768 + (HALF) * 16384 + (J) * 1024 + ldst)

  const int xo = lr & 7;
  const int aRow = (wr * 128 + lr) * 128;
  const int bRow = (wc * 64 + lr) * 128;
#define RDA(BUFB, MI, KH) \
  (*(const short8*)(L + (BUFB) + aRow + (MI) * 2048 + ((((KH) * 4 + lg) ^ xo) << 4)))
#define RDB(BUFB, NI, KH) \
  (*(const short8*)(L + (BUFB) + 32768 + bRow + (NI) * 2048 + ((((KH) * 4 + lg) ^ xo) << 4)))

  f32x4 acc[8][4] = {};
  const int ktiles = K >> 6;

#pragma unroll
  for (int h = 0; h < 2; ++h)
#pragma unroll
    for (int j = 0; j < 2; ++j) { STAGE(0, 0, h, j, 0); STAGE(0, 1, h, j, 0); }
  if (ktiles > 1) {
    STAGE(65536, 0, 0, 0, 1); STAGE(65536, 0, 0, 1, 1);
    asm volatile("s_waitcnt vmcnt(2)" ::: "memory");
  } else {
    asm volatile("s_waitcnt vmcnt(0)" ::: "memory");
  }
  __builtin_amdgcn_s_barrier();

  short8 afr[4][2], bfr[4][2];

#define KTILE_PHASES(CB, NB, KT, DOSTAGE)                                          \
  /* P0: read A-lo + B01; stage A-h1 */                                            \
  _Pragma("unroll") for (int mi = 0; mi < 4; ++mi)                                 \
      _Pragma("unroll") for (int kh = 0; kh < 2; ++kh)                             \
          afr[mi][kh] = RDA(CB, mi, kh);                                           \
  _Pragma("unroll") for (int ni = 0; ni < 2; ++ni)                                 \
      _Pragma("unroll") for (int kh = 0; kh < 2; ++kh)                             \
          bfr[ni][kh] = RDB(CB, ni, kh);                                           \
  if (DOSTAGE) { STAGE(NB, 0, 1, 0, (KT) + 1); STAGE(NB, 0, 1, 1, (KT) + 1); }     \
  __builtin_amdgcn_s_setprio(1);                                                   \
  _Pragma("unroll") for (int mi = 0; mi < 4; ++mi)                                 \
      _Pragma("unroll") for (int ni = 0; ni < 2; ++ni)                             \
          _Pragma("unroll") for (int kh = 0; kh < 2; ++kh)                         \
              acc[mi][ni] = __builtin_amdgcn_mfma_f32_16x16x32_bf16(               \
                  afr[mi][kh], bfr[ni][kh], acc[mi][ni], 0, 0, 0);                 \
  __builtin_amdgcn_s_setprio(0);                                                   \
  /* P1: read B23; stage B-h0 */                                                   \
  _Pragma("unroll") for (int ni = 2; ni < 4; ++ni)                                 \
      _Pragma("unroll") for (int kh = 0; kh < 2; ++kh)                             \
          bfr[ni][kh] = RDB(CB, ni, kh);                                           \
  if (DOSTAGE) { STAGE(NB, 1, 0, 0, (KT) + 1); STAGE(NB, 1, 0, 1, (KT) + 1); }     \
  __builtin_amdgcn_s_setprio(1);                                                   \
  _Pragma("unroll") for (int mi = 0; mi < 4; ++mi)                                 \
      _Pragma("unroll") for (int ni = 2; ni < 4; ++ni)                             \
          _Pragma("unroll") for (int kh = 0; kh < 2; ++kh)                         \
              acc[mi][ni] = __builtin_amdgcn_mfma_f32_16x16x32_bf16(               \
                  afr[mi][kh], bfr[ni][kh], acc[mi][ni], 0, 0, 0);                 \
  __builtin_amdgcn_s_setprio(0);                                                   \
  /* P2: read A-hi; stage B-h1 */                                                  \
  _Pragma("unroll") for (int mi = 0; mi < 4; ++mi)                                 \
      _Pragma("unroll") for (int kh = 0; kh < 2; ++kh)                             \
          afr[mi][kh] = RDA(CB, mi + 4, kh);                                       \
  if (DOSTAGE) { STAGE(NB, 1, 1, 0, (KT) + 1); STAGE(NB, 1, 1, 1, (KT) + 1); }     \
  __builtin_amdgcn_s_setprio(1);                                                   \
  _Pragma("unroll") for (int mi = 0; mi < 4; ++mi)                                 \
      _Pragma("unroll") for (int ni = 2; ni < 4; ++ni)                             \
          _Pragma("unroll") for (int kh = 0; kh < 2; ++kh)                         \
              acc[mi + 4][ni] = __builtin_amdgcn_mfma_f32_16x16x32_bf16(           \
                  afr[mi][kh], bfr[ni][kh], acc[mi + 4][ni], 0, 0, 0);             \
  __builtin_amdgcn_s_setprio(0);                                                   \
  /* P3: no reads, no stage */                                                     \
  __builtin_amdgcn_s_setprio(1);                                                   \
  _Pragma("unroll") for (int mi = 0; mi < 4; ++mi)                                 \
      _Pragma("unroll") for (int ni = 0; ni < 2; ++ni)                             \
          _Pragma("unroll") for (int kh = 0; kh < 2; ++kh)                         \
              acc[mi + 4][ni] = __builtin_amdgcn_mfma_f32_16x16x32_bf16(           \
                  afr[mi][kh], bfr[ni][kh], acc[mi + 4][ni], 0, 0, 0);             \
  __builtin_amdgcn_s_setprio(0);

  int c = 0;
  for (int kt = 0; kt < ktiles - 1; ++kt) {
    const int cb = c << 16, nb = (c ^ 1) << 16;
    KTILE_PHASES(cb, nb, kt, true)
    __builtin_amdgcn_s_barrier();   // all waves done reading buf c
    if (kt + 2 < ktiles) {
      STAGE(cb, 0, 0, 0, kt + 2); STAGE(cb, 0, 0, 1, kt + 2);
      asm volatile("s_waitcnt vmcnt(2)" ::: "memory");
    } else {
      asm volatile("s_waitcnt vmcnt(0)" ::: "memory");
    }
    __builtin_amdgcn_s_barrier();
    c ^= 1;
  }
  {
    const int cb = c << 16, nb = 0;
    KTILE_PHASES(cb, nb, 0, false)
  }
#undef KTILE_PHASES
#undef STAGE
#undef RDA
#undef RDB

#pragma unroll
  for (int mi = 0; mi < 8; ++mi)
#pragma unroll
    for (int rr = 0; rr < 4; ++rr) {
      int mg = bm * 256 + wr * 128 + mi * 16 + lg * 4 + rr;
#pragma unroll
      for (int ni = 0; ni < 4; ++ni)
        outF[(size_t)mg * N + bn * 256 + wc * 64 + ni * 16 + lr] = acc[mi][ni][rr];
    }
}

// ---------- causal flash attention ----------
// R10 T12 in-register softmax + R5 triple-buffer counted-vmcnt staging (best
// measured). (256,4) VGPR-cap spills to scratch (R13: attn 517us) -- keep (256,3).
__global__ __launch_bounds__(256, 3) void k_attn(
    const unsigned short* __restrict__ Q,
    const unsigned short* __restrict__ Kc,
    const unsigned short* __restrict__ Vt,
    unsigned short* __restrict__ Y) {
  const int qt_h = 15 - (blockIdx.x >> 6);
  const int bh = blockIdx.x & 63;
  const int q0 = qt_h * 128;
  const int t = threadIdx.x;
  const int w = t >> 6, lane = t & 63;
  const int lr = lane & 15, lg = lane >> 4;
  const int b = bh >> 4, h = bh & 15;

  __shared__ unsigned short lK[3][32 * 128];    // swz byte ^= ((row&7)<<4)
  __shared__ unsigned short lVt[3][128 * 32];   // linear

  const char* kg = (const char*)(Kc + (size_t)bh * CS * CHD);
  const char* vtg = (const char*)(Vt + (size_t)bh * CHD * CS);

  short8 qf[2][4];
#pragma unroll
  for (int qt = 0; qt < 2; ++qt)
#pragma unroll
    for (int ks = 0; ks < 4; ++ks)
      qf[qt][ks] = *(const short8*)(Q + ((size_t)bh * CS + q0 + w * 32 + qt * 16 + lr) * CHD + ks * 32 + lg * 8);

  f32x4 accy[2][8] = {};
  f32x4 accl[2] = {};
  float m[2] = {-1e30f, -1e30f};  // per-lane running max for q-row = lr (per qt)

  short8 vone;
  {
    short o16 = (lr == 0) ? (short)0x3F80 : (short)0;  // bf16(1.0) in col 0
#pragma unroll
    for (int e = 0; e < 8; ++e) vone[e] = o16;
  }

  const int nch = 4 * qt_h + 4;
  const int qmaxw = q0 + w * 32 + 31;

  auto stage = [&](int ch, int buf) {
    const int kv0 = ch * 32;
    char* dK = (char*)lK[buf];
    char* dV = (char*)lVt[buf];
#pragma unroll
    for (int i = 0; i < 2; ++i) {
      int kr = w * 8 + i * 4 + lg;
      GLOAD_LDS16(kg + (size_t)(kv0 + kr) * 256 + ((lr * 16) ^ ((kr & 7) << 4)),
                  dK + w * 2048 + i * 1024 + lane * 16);
    }
#pragma unroll
    for (int i = 0; i < 2; ++i) {
      int vd = w * 32 + i * 16 + (lane >> 2);
      GLOAD_LDS16(vtg + (size_t)vd * 4096 + (size_t)kv0 * 2 + (lane & 3) * 16,
                  dV + w * 2048 + i * 1024 + lane * 16);
    }
  };

  stage(0, 0);
  stage(1, 1);
  int cur = 0, nxt = 2;  // buf of ch, buf of ch+2 (rotating mod 3)
  for (int ch = 0; ch < nch; ++ch) {
    if (ch + 1 < nch) {
      asm volatile("s_waitcnt vmcnt(4)" ::: "memory");  // ch landed; ch+1 in flight
    } else {
      asm volatile("s_waitcnt vmcnt(0)" ::: "memory");
    }
    __builtin_amdgcn_s_barrier();       // all waves' stage(ch) visible
    if (ch + 2 < nch) stage(ch + 2, nxt);

    const int kv0 = ch * 32;
    const unsigned short* bK = lK[cur];
    const unsigned short* bV = lVt[cur];
    cur = cur == 2 ? 0 : cur + 1;
    nxt = nxt == 2 ? 0 : nxt + 1;

    if (kv0 <= qmaxw) {  // wave-uniform
      // ---- QK^T, swapped: S^T[kv][q]; col(lr)=q, row(lg*4+r)=kv ----
      f32x4 sv[2][2] = {};
#pragma unroll
      for (int kvt = 0; kvt < 2; ++kvt) {
        short8 kf[4];
#pragma unroll
        for (int ks = 0; ks < 4; ++ks) {
          int row = kvt * 16 + lr;
          kf[ks] = *(const short8*)((const char*)bK + row * 256 + ((ks * 64 + lg * 16) ^ ((row & 7) << 4)));
        }
#pragma unroll
        for (int qt = 0; qt < 2; ++qt)
#pragma unroll
          for (int ks = 0; ks < 4; ++ks)
            sv[qt][kvt] = __builtin_amdgcn_mfma_f32_16x16x32_bf16(kf[ks], qf[qt][ks], sv[qt][kvt], 0, 0, 0);
      }

      // ---- mask + lane-local row max (8 values) + cross-group reduce ----
      float p8[2][8];
      float pm[2];
      bool need = false;
#pragma unroll
      for (int qt = 0; qt < 2; ++qt) {
        const int qi = q0 + w * 32 + qt * 16 + lr;
        float mx = -1e30f;
#pragma unroll
        for (int kvt = 0; kvt < 2; ++kvt)
#pragma unroll
          for (int r = 0; r < 4; ++r) {
            int kv = kv0 + kvt * 16 + lg * 4 + r;
            float s = (kv <= qi) ? sv[qt][kvt][r] : -1e30f;
            p8[qt][kvt * 4 + r] = s;
            mx = fmaxf(mx, s);
          }
        mx = fmaxf(mx, __shfl_xor(mx, 32, 64));
        mx = fmaxf(mx, __shfl_xor(mx, 16, 64));
        pm[qt] = mx;
        need = need || (mx > m[qt] + 8.0f);
      }

      // ---- rare rescale (defer-max THR=8); fr must go to accy layout ----
      if (__any((int)need)) {
#pragma unroll
        for (int qt = 0; qt < 2; ++qt) {
          float nm = fmaxf(m[qt], pm[qt]);
          float fr = __expf(m[qt] - nm);
          m[qt] = nm;
#pragma unroll
          for (int r = 0; r < 4; ++r) {
            // accy row r holds q = lg*4+r; fetch fr from lane (lg*4+r)
            int idx = (((lane >> 4) << 2) + r) << 2;
            float frT = __builtin_bit_cast(float,
                __builtin_amdgcn_ds_bpermute(idx, __builtin_bit_cast(int, fr)));
#pragma unroll
            for (int dt = 0; dt < 8; ++dt) accy[qt][dt][r] *= frT;
            accl[qt][r] *= frT;
          }
        }
      }

      // ---- P = exp(s-m), pack to bf16 words, shfl into PV A-fragment ----
      short8 pa[2];
      const int sA = lr + ((lane & 16) << 1);  // lr + (lg&1)*32
      const int sB = sA + 16;
      const bool hi = (lane >= 32);
#pragma unroll
      for (int qt = 0; qt < 2; ++qt) {
        float pe0 = __expf(p8[qt][0] - m[qt]);
        float pe1 = __expf(p8[qt][1] - m[qt]);
        float pe2 = __expf(p8[qt][2] - m[qt]);
        float pe3 = __expf(p8[qt][3] - m[qt]);
        float pe4 = __expf(p8[qt][4] - m[qt]);
        float pe5 = __expf(p8[qt][5] - m[qt]);
        float pe6 = __expf(p8[qt][6] - m[qt]);
        float pe7 = __expf(p8[qt][7] - m[qt]);
        unsigned w0 = pkbf(pe0, pe1);  // kv (lg*4+0, +1), kvt0
        unsigned w1 = pkbf(pe2, pe3);  // kv (lg*4+2, +3), kvt0
        unsigned w2 = pkbf(pe4, pe5);  // kv 16+(lg*4+0, +1), kvt1
        unsigned w3 = pkbf(pe6, pe7);  // kv 16+(lg*4+2, +3), kvt1
        // X0 = kv(lg*8+0,+1): lg0<-w0@lg0, lg1<-w0@lg2, lg2<-w2@lg0, lg3<-w2@lg2
        unsigned a0 = (unsigned)__shfl((int)w0, sA, 64);
        unsigned a2 = (unsigned)__shfl((int)w2, sA, 64);
        unsigned b0 = (unsigned)__shfl((int)w1, sA, 64);
        unsigned b2 = (unsigned)__shfl((int)w3, sA, 64);
        // X2 = kv(lg*8+4,+5): lg0<-w0@lg1, lg1<-w0@lg3, lg2<-w2@lg1, lg3<-w2@lg3
        unsigned c0 = (unsigned)__shfl((int)w0, sB, 64);
        unsigned c2 = (unsigned)__shfl((int)w2, sB, 64);
        unsigned d0 = (unsigned)__shfl((int)w1, sB, 64);
        unsigned d2 = (unsigned)__shfl((int)w3, sB, 64);
        int4v xi;
        xi[0] = (int)(hi ? a2 : a0);
        xi[1] = (int)(hi ? b2 : b0);
        xi[2] = (int)(hi ? c2 : c0);
        xi[3] = (int)(hi ? d2 : d0);
        pa[qt] = __builtin_bit_cast(short8, xi);  // elems e = kv lg*8+e, q=lr
      }

      // ---- PV + ones-column row-sum ----
#pragma unroll
      for (int dt = 0; dt < 8; ++dt) {
        short8 vf = *(const short8*)((const char*)bV + (dt * 16 + lr) * 64 + lg * 16);
#pragma unroll
        for (int qt = 0; qt < 2; ++qt)
          accy[qt][dt] = __builtin_amdgcn_mfma_f32_16x16x32_bf16(pa[qt], vf, accy[qt][dt], 0, 0, 0);
      }
#pragma unroll
      for (int qt = 0; qt < 2; ++qt)
        accl[qt] = __builtin_amdgcn_mfma_f32_16x16x32_bf16(pa[qt], vone, accl[qt], 0, 0, 0);
    }
  }

#pragma unroll
  for (int qt = 0; qt < 2; ++qt)
#pragma unroll
    for (int r = 0; r < 4; ++r) {
      float lsum = accl[qt][r];
      lsum = __shfl(lsum, lane & 48, 64);  // broadcast from col-0 lane of this group
      float inv = 1.0f / lsum;
      int qrow = q0 + w * 32 + qt * 16 + lg * 4 + r;
      unsigned short* yr = Y + ((size_t)(b * CS + qrow)) * CD + h * CHD;
#pragma unroll
      for (int dt = 0; dt < 8; ++dt)
        yr[dt * 16 + lr] = f2bf(accy[qt][dt][r] * inv);
    }
}

extern "C" void kernel_launch(void* const* d_in, const int* in_sizes, int n_in,
                              void* d_out, int out_size, void* d_ws, size_t ws_size,
                              hipStream_t stream) {
  const float* x = (const float*)d_in[0];
  const int* positions = (const int*)d_in[1];
  // d_in[2] = causal mask (structural; unused)
  const float* Wqkv = (const float*)d_in[3];
  const float* Wout = (const float*)d_in[4];
  float* out = (float*)d_out;

  char* ws = (char*)d_ws;
  size_t off = 0;
  auto alloc = [&](size_t bytes) {
    char* p = ws + off;
    off += (bytes + 255) & ~(size_t)255;
    return p;
  };
  unsigned short* q_bf = (unsigned short*)alloc((size_t)64 * CS * CHD * 2);  // 32 MB
  unsigned short* k_bf = (unsigned short*)alloc((size_t)64 * CS * CHD * 2);  // 32 MB
  unsigned short* v_bf = (unsigned short*)alloc((size_t)64 * CS * CHD * 2);  // 32 MB: Vt (GEMM1 epi)
  unsigned short* xw = (unsigned short*)alloc((size_t)8192 * CD * 2);        // 32 MB: x_bf, later Y
  unsigned short* wT = (unsigned short*)alloc((size_t)CN3 * CD * 2);         // 24 MB
  float2* tab = (float2*)alloc((size_t)CS * 64 * sizeof(float2));            // 1 MB

  // no memsets: positions = arange(S) -> GEMM1 epilogue writes every k/v element

  k_cvt<<<8192, 256, 0, stream>>>(x, xw, 8192 * CD);
  k_transcvt<<<dim3(CN3 / 32, CD / 32), 256, 0, stream>>>(Wqkv, wT, CD, CN3);
  k_ropetab<<<CS, 64, 0, stream>>>(tab);
  // GEMM1 (BK=32, 2 blocks/CU): fused RoPE(q,k)+q-scale; V written as Vt
  k_gemm32<<<768, 512, 0, stream>>>(xw, wT, q_bf, k_bf, v_bf,
                                    positions, tab, CD, 24);
  k_transcvt<<<dim3(CD / 32, CD / 32), 256, 0, stream>>>(Wout, wT, CD, CD);
  k_attn<<<1024, 256, 0, stream>>>(q_bf, k_bf, v_bf, xw);
  k_gemm256<1><<<256, 512, 0, stream>>>(xw, wT, out, 8192, CD, CD, 8);
}

// Round 9
// 404.724 us; speedup vs baseline: 1.0495x; 1.0495x over previous
//
#include <hip/hip_runtime.h>
#include <hip/hip_bf16.h>
#include <cstdint>
#include <cstddef>

// B=4, S=2048, H=16, hd=128, D=2048, 3D=6144
constexpr int CS = 2048;
constexpr int CHD = 128;
constexpr int CD = 2048;
constexpr int CN3 = 6144;

typedef __attribute__((ext_vector_type(8))) short short8;
typedef __attribute__((ext_vector_type(4))) float f32x4;
typedef __attribute__((ext_vector_type(4))) int int4v;

#define GLOAD_LDS16(g, l) __builtin_amdgcn_global_load_lds( \
    (const __attribute__((address_space(1))) void*)(g),      \
    (__attribute__((address_space(3))) void*)(l), 16, 0, 0)

__device__ __forceinline__ unsigned short f2bf(float f) {
  union { float f; unsigned u; } v; v.f = f;
  unsigned r = v.u + 0x7fffu + ((v.u >> 16) & 1u);
  return (unsigned short)(r >> 16);
}
// pack two f32 -> dword of 2x bf16 (lo=a, hi=b) using the same RNE bit-math
__device__ __forceinline__ unsigned pkbf(float a, float b) {
  return (unsigned)f2bf(a) | ((unsigned)f2bf(b) << 16);
}

// lane^1 value (quad_perm [1,0,3,2]) -- used by GEMM1 RoPE epilogue
__device__ __forceinline__ float dpp_xor1(float x) {
  return __builtin_bit_cast(float, __builtin_amdgcn_update_dpp(
      __builtin_bit_cast(int, x), __builtin_bit_cast(int, x), 0xB1, 0xf, 0xf, true));
}

// ---------- f32 -> bf16 elementwise ----------
__global__ __launch_bounds__(256) void k_cvt(const float* __restrict__ in,
                                             unsigned short* __restrict__ out, int n) {
  int i = (blockIdx.x * 256 + threadIdx.x) * 8;
  if (i >= n) return;
  float4 a = *(const float4*)(in + i);
  float4 b = *(const float4*)(in + i + 4);
  short8 o;
  o[0] = (short)f2bf(a.x); o[1] = (short)f2bf(a.y);
  o[2] = (short)f2bf(a.z); o[3] = (short)f2bf(a.w);
  o[4] = (short)f2bf(b.x); o[5] = (short)f2bf(b.y);
  o[6] = (short)f2bf(b.z); o[7] = (short)f2bf(b.w);
  *(short8*)(out + i) = o;
}

// ---------- transpose + convert: in [R][C] f32 -> out [C][R] bf16 ----------
__global__ __launch_bounds__(256) void k_transcvt(const float* __restrict__ in,
                                                  unsigned short* __restrict__ out,
                                                  int R, int C) {
  __shared__ float tile[32][33];
  int c0 = blockIdx.x * 32, r0 = blockIdx.y * 32;
  int tx = threadIdx.x & 31, ty = threadIdx.x >> 5;  // 32 x 8
#pragma unroll
  for (int j = 0; j < 4; ++j)
    tile[ty + 8 * j][tx] = in[(size_t)(r0 + ty + 8 * j) * C + c0 + tx];
  __syncthreads();
#pragma unroll
  for (int j = 0; j < 4; ++j)
    out[(size_t)(c0 + ty + 8 * j) * R + r0 + tx] = f2bf(tile[tx][ty + 8 * j]);
}

// ---------- RoPE cos/sin table [2048][64] float2 ----------
__global__ void k_ropetab(float2* __restrict__ tab) {
  int p = blockIdx.x, c = threadIdx.x;  // 64 threads
  float inv = powf(10000.0f, -(float)(2 * c) / 128.0f);
  float a = (float)p * inv;
  tab[p * 64 + c] = make_float2(cosf(a), sinf(a));
}

// ---------- 256x256-tile BK=64 bf16 MFMA GEMM, 8 waves, dbuf + counted vmcnt ----------
// R3-verified loose interior (199.7us, MfmaUtil 45). FOUR schedule/geometry
// perturbations all regressed: strict per-phase barriers (R6: 229->245,
// R8: 199.7->215.7), early-issue of all 6 stages (R11: ->211), BK=32 for
// 2 blocks/CU (R14: ->222; VGPR file, not LDS, binds occupancy at 8-wave
// blocks so the 2nd block never materialized). Do not touch the schedule.
// R15: L2-supertiled block mapping -- each XCD's ~32 concurrent blocks form
// a 4bm x 8bn supertile (A 4MB + B 8MB working set) instead of 1.3bm x 24bn
// (25MB of B streaming through the 4MB L2). Cuts TCC refetch (FETCH 322MB
// at R7) and so the L3/HBM latency the per-tile vmcnt drain exposes. Pure
// bijective remap; "which = bn>>3" stays block-uniform.
// EPI=0 epilogue fuses RoPE (q,k) + q-scale; V blocks (which==2) transpose
// the 256x256 tile through the (now free) 128KB LDS and write Vt [bh][d][s].
template <int EPI>
__global__ __launch_bounds__(512, 2) void k_gemm256(
    const unsigned short* __restrict__ A,
    const unsigned short* __restrict__ Bt,
    float* __restrict__ outF,
    unsigned short* __restrict__ outQ,
    unsigned short* __restrict__ outK,
    unsigned short* __restrict__ outV,
    const int* __restrict__ positions,
    const float2* __restrict__ tab,
    int M, int N, int K, int nbn) {
  (void)nbn;
  const int wg = blockIdx.x;
  const int l = wg >> 3;                       // per-XCD local id
  const int bm = (wg & 7) * 4 + ((l >> 3) & 3);  // 4 bm-rows per XCD
  const int bn = (l >> 5) * 8 + (l & 7);         // 8-wide bn supercolumns

  const int t = threadIdx.x;
  const int w = t >> 6, lane = t & 63;
  const int wr = w >> 2, wc = w & 3;       // 2 x 4 wave grid
  const int lr = lane & 15, lg = lane >> 4;

  __shared__ char L[131072];  // [buf:64K][op:32K = 256 rows x 128B]

  const size_t Kb = (size_t)K * 2;
  const int srl = w * 16 + (lane >> 3);
  const int sch = ((lane & 7) ^ (lane >> 3)) * 16;
  const char* gA = (const char*)A + (size_t)(bm * 256 + srl) * Kb + sch;
  const char* gB = (const char*)Bt + (size_t)(bn * 256 + srl) * Kb + sch;
  const int ldst = w * 2048 + lane * 16;

#define STAGE(BUFB, OP, HALF, J, KT)                                               \
  GLOAD_LDS16(((OP) ? gB : gA) + (size_t)((HALF) * 128 + (J) * 8) * Kb +           \
                  (size_t)(KT) * 128,                                              \
              L + (BUFB) + (OP) * 32768 + (HALF) * 16384 + (J) * 1024 + ldst)

  const int xo = lr & 7;
  const int aRow = (wr * 128 + lr) * 128;
  const int bRow = (wc * 64 + lr) * 128;
#define RDA(BUFB, MI, KH) \
  (*(const short8*)(L + (BUFB) + aRow + (MI) * 2048 + ((((KH) * 4 + lg) ^ xo) << 4)))
#define RDB(BUFB, NI, KH) \
  (*(const short8*)(L + (BUFB) + 32768 + bRow + (NI) * 2048 + ((((KH) * 4 + lg) ^ xo) << 4)))

  f32x4 acc[8][4] = {};
  const int ktiles = K >> 6;

#pragma unroll
  for (int h = 0; h < 2; ++h)
#pragma unroll
    for (int j = 0; j < 2; ++j) { STAGE(0, 0, h, j, 0); STAGE(0, 1, h, j, 0); }
  if (ktiles > 1) {
    STAGE(65536, 0, 0, 0, 1); STAGE(65536, 0, 0, 1, 1);
    asm volatile("s_waitcnt vmcnt(2)" ::: "memory");
  } else {
    asm volatile("s_waitcnt vmcnt(0)" ::: "memory");
  }
  __builtin_amdgcn_s_barrier();

  short8 afr[4][2], bfr[4][2];

#define KTILE_PHASES(CB, NB, KT, DOSTAGE)                                          \
  /* P0: read A-lo + B01; stage A-h1 */                                            \
  _Pragma("unroll") for (int mi = 0; mi < 4; ++mi)                                 \
      _Pragma("unroll") for (int kh = 0; kh < 2; ++kh)                             \
          afr[mi][kh] = RDA(CB, mi, kh);                                           \
  _Pragma("unroll") for (int ni = 0; ni < 2; ++ni)                                 \
      _Pragma("unroll") for (int kh = 0; kh < 2; ++kh)                             \
          bfr[ni][kh] = RDB(CB, ni, kh);                                           \
  if (DOSTAGE) { STAGE(NB, 0, 1, 0, (KT) + 1); STAGE(NB, 0, 1, 1, (KT) + 1); }     \
  __builtin_amdgcn_s_setprio(1);                                                   \
  _Pragma("unroll") for (int mi = 0; mi < 4; ++mi)                                 \
      _Pragma("unroll") for (int ni = 0; ni < 2; ++ni)                             \
          _Pragma("unroll") for (int kh = 0; kh < 2; ++kh)                         \
              acc[mi][ni] = __builtin_amdgcn_mfma_f32_16x16x32_bf16(               \
                  afr[mi][kh], bfr[ni][kh], acc[mi][ni], 0, 0, 0);                 \
  __builtin_amdgcn_s_setprio(0);                                                   \
  /* P1: read B23; stage B-h0 */                                                   \
  _Pragma("unroll") for (int ni = 2; ni < 4; ++ni)                                 \
      _Pragma("unroll") for (int kh = 0; kh < 2; ++kh)                             \
          bfr[ni][kh] = RDB(CB, ni, kh);                                           \
  if (DOSTAGE) { STAGE(NB, 1, 0, 0, (KT) + 1); STAGE(NB, 1, 0, 1, (KT) + 1); }     \
  __builtin_amdgcn_s_setprio(1);                                                   \
  _Pragma("unroll") for (int mi = 0; mi < 4; ++mi)                                 \
      _Pragma("unroll") for (int ni = 2; ni < 4; ++ni)                             \
          _Pragma("unroll") for (int kh = 0; kh < 2; ++kh)                         \
              acc[mi][ni] = __builtin_amdgcn_mfma_f32_16x16x32_bf16(               \
                  afr[mi][kh], bfr[ni][kh], acc[mi][ni], 0, 0, 0);                 \
  __builtin_amdgcn_s_setprio(0);                                                   \
  /* P2: read A-hi; stage B-h1 */                                                  \
  _Pragma("unroll") for (int mi = 0; mi < 4; ++mi)                                 \
      _Pragma("unroll") for (int kh = 0; kh < 2; ++kh)                             \
          afr[mi][kh] = RDA(CB, mi + 4, kh);                                       \
  if (DOSTAGE) { STAGE(NB, 1, 1, 0, (KT) + 1); STAGE(NB, 1, 1, 1, (KT) + 1); }     \
  __builtin_amdgcn_s_setprio(1);                                                   \
  _Pragma("unroll") for (int mi = 0; mi < 4; ++mi)                                 \
      _Pragma("unroll") for (int ni = 2; ni < 4; ++ni)                             \
          _Pragma("unroll") for (int kh = 0; kh < 2; ++kh)                         \
              acc[mi + 4][ni] = __builtin_amdgcn_mfma_f32_16x16x32_bf16(           \
                  afr[mi][kh], bfr[ni][kh], acc[mi + 4][ni], 0, 0, 0);             \
  __builtin_amdgcn_s_setprio(0);                                                   \
  /* P3: no reads, no stage */                                                     \
  __builtin_amdgcn_s_setprio(1);                                                   \
  _Pragma("unroll") for (int mi = 0; mi < 4; ++mi)                                 \
      _Pragma("unroll") for (int ni = 0; ni < 2; ++ni)                             \
          _Pragma("unroll") for (int kh = 0; kh < 2; ++kh)                         \
              acc[mi + 4][ni] = __builtin_amdgcn_mfma_f32_16x16x32_bf16(           \
                  afr[mi][kh], bfr[ni][kh], acc[mi + 4][ni], 0, 0, 0);             \
  __builtin_amdgcn_s_setprio(0);

  int c = 0;
  for (int kt = 0; kt < ktiles - 1; ++kt) {
    const int cb = c << 16, nb = (c ^ 1) << 16;
    KTILE_PHASES(cb, nb, kt, true)
    __builtin_amdgcn_s_barrier();   // all waves done reading buf c
    if (kt + 2 < ktiles) {
      STAGE(cb, 0, 0, 0, kt + 2); STAGE(cb, 0, 0, 1, kt + 2);
      asm volatile("s_waitcnt vmcnt(2)" ::: "memory");
    } else {
      asm volatile("s_waitcnt vmcnt(0)" ::: "memory");
    }
    __builtin_amdgcn_s_barrier();
    c ^= 1;
  }
  {
    const int cb = c << 16, nb = 0;
    KTILE_PHASES(cb, nb, 0, false)
  }
#undef KTILE_PHASES
#undef STAGE
#undef RDA
#undef RDB

  if constexpr (EPI == 0) {
    const int which = bn >> 3;  // 0=q 1=k 2=v (block-uniform: bn*256 spans one 2048-chunk)
    if (which < 2) {
      const float qsc = which ? 1.0f : 0.08838834764831845f;  // 1/sqrt(128) for q
      unsigned short* dstB = which ? outK : outQ;
#pragma unroll
      for (int mi = 0; mi < 8; ++mi)
#pragma unroll
        for (int rr = 0; rr < 4; ++rr) {
          int mg = bm * 256 + wr * 128 + mi * 16 + lg * 4 + rr;
          int bb = mg >> 11, s = mg & 2047;
          int pos = positions[s];
          int srow2 = which ? pos : s;  // k goes to cache row positions[s]
          const float2* tb = tab + pos * 64 + wc * 32 + (lr >> 1);
#pragma unroll
          for (int ni = 0; ni < 4; ++ni) {
            int cn = bn * 256 + wc * 64 + ni * 16 + lr;
            int h = (cn >> 7) & 15, d = cn & 127;
            float x = acc[mi][ni][rr];
            float p = dpp_xor1(x);          // partner element of the rope pair
            float2 cs = tb[ni * 8];         // tab[pos][d>>1]
            float y = (lr & 1) ? (x * cs.x + p * cs.y)    // odd: x1*c + x0*s
                               : (x * cs.x - p * cs.y);   // even: x0*c - x1*s
            dstB[((size_t)(bb * 16 + h) * CS + srow2) * CHD + d] = f2bf(y * qsc);
          }
        }
    } else {
      // ---- v: transpose 256x256 tile through LDS, write Vt [bh][d][s] ----
      __syncthreads();  // all waves done with K-loop LDS before overwrite
      unsigned short* TL = (unsigned short*)L;  // 256x256 bf16 = 128KB exactly
#pragma unroll
      for (int mi = 0; mi < 8; ++mi) {
        int sb = wr * 128 + mi * 16 + lg * 4;  // s_local base (mult of 4)
#pragma unroll
        for (int ni = 0; ni < 4; ++ni) {
          int vc = wc * 64 + ni * 16 + lr;     // col_local 0..255
          unsigned lo = pkbf(acc[mi][ni][0], acc[mi][ni][1]);
          unsigned hi2 = pkbf(acc[mi][ni][2], acc[mi][ni][3]);
          unsigned long long v8 = (unsigned long long)lo | ((unsigned long long)hi2 << 32);
          *(unsigned long long*)(TL + vc * 256 + (sb ^ ((vc & 7) << 3))) = v8;
        }
      }
      __syncthreads();
      const int row = t >> 1, half = t & 1;    // row = col_local = (h,d)
      const int bb = bm >> 3, s0 = (bm & 7) * 256;
      const int h0 = bn * 2 - 32;              // bn in [16,24)
      unsigned short* vrow = outV +
          ((size_t)((bb * 16 + h0 + (row >> 7)) * 128 + (row & 127))) * CS + s0 + half * 128;
#pragma unroll
      for (int j = 0; j < 16; ++j) {
        short8 v = *(const short8*)(TL + row * 256 + ((half * 128 + j * 8) ^ ((row & 7) << 3)));
        *(short8*)(vrow + j * 8) = v;
      }
    }
  } else {
#pragma unroll
    for (int mi = 0; mi < 8; ++mi)
#pragma unroll
      for (int rr = 0; rr < 4; ++rr) {
        int mg = bm * 256 + wr * 128 + mi * 16 + lg * 4 + rr;
#pragma unroll
        for (int ni = 0; ni < 4; ++ni)
          outF[(size_t)mg * N + bn * 256 + wc * 64 + ni * 16 + lr] = acc[mi][ni][rr];
      }
  }
}

// ---------- causal flash attention ----------
// R10 T12 in-register softmax + R5 triple-buffer counted-vmcnt staging (best
// measured). (256,4) VGPR-cap spills to scratch (R13: attn 517us) -- keep (256,3).
__global__ __launch_bounds__(256, 3) void k_attn(
    const unsigned short* __restrict__ Q,
    const unsigned short* __restrict__ Kc,
    const unsigned short* __restrict__ Vt,
    unsigned short* __restrict__ Y) {
  const int qt_h = 15 - (blockIdx.x >> 6);
  const int bh = blockIdx.x & 63;
  const int q0 = qt_h * 128;
  const int t = threadIdx.x;
  const int w = t >> 6, lane = t & 63;
  const int lr = lane & 15, lg = lane >> 4;
  const int b = bh >> 4, h = bh & 15;

  __shared__ unsigned short lK[3][32 * 128];    // swz byte ^= ((row&7)<<4)
  __shared__ unsigned short lVt[3][128 * 32];   // linear

  const char* kg = (const char*)(Kc + (size_t)bh * CS * CHD);
  const char* vtg = (const char*)(Vt + (size_t)bh * CHD * CS);

  short8 qf[2][4];
#pragma unroll
  for (int qt = 0; qt < 2; ++qt)
#pragma unroll
    for (int ks = 0; ks < 4; ++ks)
      qf[qt][ks] = *(const short8*)(Q + ((size_t)bh * CS + q0 + w * 32 + qt * 16 + lr) * CHD + ks * 32 + lg * 8);

  f32x4 accy[2][8] = {};
  f32x4 accl[2] = {};
  float m[2] = {-1e30f, -1e30f};  // per-lane running max for q-row = lr (per qt)

  short8 vone;
  {
    short o16 = (lr == 0) ? (short)0x3F80 : (short)0;  // bf16(1.0) in col 0
#pragma unroll
    for (int e = 0; e < 8; ++e) vone[e] = o16;
  }

  const int nch = 4 * qt_h + 4;
  const int qmaxw = q0 + w * 32 + 31;

  auto stage = [&](int ch, int buf) {
    const int kv0 = ch * 32;
    char* dK = (char*)lK[buf];
    char* dV = (char*)lVt[buf];
#pragma unroll
    for (int i = 0; i < 2; ++i) {
      int kr = w * 8 + i * 4 + lg;
      GLOAD_LDS16(kg + (size_t)(kv0 + kr) * 256 + ((lr * 16) ^ ((kr & 7) << 4)),
                  dK + w * 2048 + i * 1024 + lane * 16);
    }
#pragma unroll
    for (int i = 0; i < 2; ++i) {
      int vd = w * 32 + i * 16 + (lane >> 2);
      GLOAD_LDS16(vtg + (size_t)vd * 4096 + (size_t)kv0 * 2 + (lane & 3) * 16,
                  dV + w * 2048 + i * 1024 + lane * 16);
    }
  };

  stage(0, 0);
  stage(1, 1);
  int cur = 0, nxt = 2;  // buf of ch, buf of ch+2 (rotating mod 3)
  for (int ch = 0; ch < nch; ++ch) {
    if (ch + 1 < nch) {
      asm volatile("s_waitcnt vmcnt(4)" ::: "memory");  // ch landed; ch+1 in flight
    } else {
      asm volatile("s_waitcnt vmcnt(0)" ::: "memory");
    }
    __builtin_amdgcn_s_barrier();       // all waves' stage(ch) visible
    if (ch + 2 < nch) stage(ch + 2, nxt);

    const int kv0 = ch * 32;
    const unsigned short* bK = lK[cur];
    const unsigned short* bV = lVt[cur];
    cur = cur == 2 ? 0 : cur + 1;
    nxt = nxt == 2 ? 0 : nxt + 1;

    if (kv0 <= qmaxw) {  // wave-uniform
      // ---- QK^T, swapped: S^T[kv][q]; col(lr)=q, row(lg*4+r)=kv ----
      f32x4 sv[2][2] = {};
#pragma unroll
      for (int kvt = 0; kvt < 2; ++kvt) {
        short8 kf[4];
#pragma unroll
        for (int ks = 0; ks < 4; ++ks) {
          int row = kvt * 16 + lr;
          kf[ks] = *(const short8*)((const char*)bK + row * 256 + ((ks * 64 + lg * 16) ^ ((row & 7) << 4)));
        }
#pragma unroll
        for (int qt = 0; qt < 2; ++qt)
#pragma unroll
          for (int ks = 0; ks < 4; ++ks)
            sv[qt][kvt] = __builtin_amdgcn_mfma_f32_16x16x32_bf16(kf[ks], qf[qt][ks], sv[qt][kvt], 0, 0, 0);
      }

      // ---- mask + lane-local row max (8 values) + cross-group reduce ----
      float p8[2][8];
      float pm[2];
      bool need = false;
#pragma unroll
      for (int qt = 0; qt < 2; ++qt) {
        const int qi = q0 + w * 32 + qt * 16 + lr;
        float mx = -1e30f;
#pragma unroll
        for (int kvt = 0; kvt < 2; ++kvt)
#pragma unroll
          for (int r = 0; r < 4; ++r) {
            int kv = kv0 + kvt * 16 + lg * 4 + r;
            float s = (kv <= qi) ? sv[qt][kvt][r] : -1e30f;
            p8[qt][kvt * 4 + r] = s;
            mx = fmaxf(mx, s);
          }
        mx = fmaxf(mx, __shfl_xor(mx, 32, 64));
        mx = fmaxf(mx, __shfl_xor(mx, 16, 64));
        pm[qt] = mx;
        need = need || (mx > m[qt] + 8.0f);
      }

      // ---- rare rescale (defer-max THR=8); fr must go to accy layout ----
      if (__any((int)need)) {
#pragma unroll
        for (int qt = 0; qt < 2; ++qt) {
          float nm = fmaxf(m[qt], pm[qt]);
          float fr = __expf(m[qt] - nm);
          m[qt] = nm;
#pragma unroll
          for (int r = 0; r < 4; ++r) {
            // accy row r holds q = lg*4+r; fetch fr from lane (lg*4+r)
            int idx = (((lane >> 4) << 2) + r) << 2;
            float frT = __builtin_bit_cast(float,
                __builtin_amdgcn_ds_bpermute(idx, __builtin_bit_cast(int, fr)));
#pragma unroll
            for (int dt = 0; dt < 8; ++dt) accy[qt][dt][r] *= frT;
            accl[qt][r] *= frT;
          }
        }
      }

      // ---- P = exp(s-m), pack to bf16 words, shfl into PV A-fragment ----
      short8 pa[2];
      const int sA = lr + ((lane & 16) << 1);  // lr + (lg&1)*32
      const int sB = sA + 16;
      const bool hi = (lane >= 32);
#pragma unroll
      for (int qt = 0; qt < 2; ++qt) {
        float pe0 = __expf(p8[qt][0] - m[qt]);
        float pe1 = __expf(p8[qt][1] - m[qt]);
        float pe2 = __expf(p8[qt][2] - m[qt]);
        float pe3 = __expf(p8[qt][3] - m[qt]);
        float pe4 = __expf(p8[qt][4] - m[qt]);
        float pe5 = __expf(p8[qt][5] - m[qt]);
        float pe6 = __expf(p8[qt][6] - m[qt]);
        float pe7 = __expf(p8[qt][7] - m[qt]);
        unsigned w0 = pkbf(pe0, pe1);  // kv (lg*4+0, +1), kvt0
        unsigned w1 = pkbf(pe2, pe3);  // kv (lg*4+2, +3), kvt0
        unsigned w2 = pkbf(pe4, pe5);  // kv 16+(lg*4+0, +1), kvt1
        unsigned w3 = pkbf(pe6, pe7);  // kv 16+(lg*4+2, +3), kvt1
        // X0 = kv(lg*8+0,+1): lg0<-w0@lg0, lg1<-w0@lg2, lg2<-w2@lg0, lg3<-w2@lg2
        unsigned a0 = (unsigned)__shfl((int)w0, sA, 64);
        unsigned a2 = (unsigned)__shfl((int)w2, sA, 64);
        unsigned b0 = (unsigned)__shfl((int)w1, sA, 64);
        unsigned b2 = (unsigned)__shfl((int)w3, sA, 64);
        // X2 = kv(lg*8+4,+5): lg0<-w0@lg1, lg1<-w0@lg3, lg2<-w2@lg1, lg3<-w2@lg3
        unsigned c0 = (unsigned)__shfl((int)w0, sB, 64);
        unsigned c2 = (unsigned)__shfl((int)w2, sB, 64);
        unsigned d0 = (unsigned)__shfl((int)w1, sB, 64);
        unsigned d2 = (unsigned)__shfl((int)w3, sB, 64);
        int4v xi;
        xi[0] = (int)(hi ? a2 : a0);
        xi[1] = (int)(hi ? b2 : b0);
        xi[2] = (int)(hi ? c2 : c0);
        xi[3] = (int)(hi ? d2 : d0);
        pa[qt] = __builtin_bit_cast(short8, xi);  // elems e = kv lg*8+e, q=lr
      }

      // ---- PV + ones-column row-sum ----
#pragma unroll
      for (int dt = 0; dt < 8; ++dt) {
        short8 vf = *(const short8*)((const char*)bV + (dt * 16 + lr) * 64 + lg * 16);
#pragma unroll
        for (int qt = 0; qt < 2; ++qt)
          accy[qt][dt] = __builtin_amdgcn_mfma_f32_16x16x32_bf16(pa[qt], vf, accy[qt][dt], 0, 0, 0);
      }
#pragma unroll
      for (int qt = 0; qt < 2; ++qt)
        accl[qt] = __builtin_amdgcn_mfma_f32_16x16x32_bf16(pa[qt], vone, accl[qt], 0, 0, 0);
    }
  }

#pragma unroll
  for (int qt = 0; qt < 2; ++qt)
#pragma unroll
    for (int r = 0; r < 4; ++r) {
      float lsum = accl[qt][r];
      lsum = __shfl(lsum, lane & 48, 64);  // broadcast from col-0 lane of this group
      float inv = 1.0f / lsum;
      int qrow = q0 + w * 32 + qt * 16 + lg * 4 + r;
      unsigned short* yr = Y + ((size_t)(b * CS + qrow)) * CD + h * CHD;
#pragma unroll
      for (int dt = 0; dt < 8; ++dt)
        yr[dt * 16 + lr] = f2bf(accy[qt][dt][r] * inv);
    }
}

extern "C" void kernel_launch(void* const* d_in, const int* in_sizes, int n_in,
                              void* d_out, int out_size, void* d_ws, size_t ws_size,
                              hipStream_t stream) {
  const float* x = (const float*)d_in[0];
  const int* positions = (const int*)d_in[1];
  // d_in[2] = causal mask (structural; unused)
  const float* Wqkv = (const float*)d_in[3];
  const float* Wout = (const float*)d_in[4];
  float* out = (float*)d_out;

  char* ws = (char*)d_ws;
  size_t off = 0;
  auto alloc = [&](size_t bytes) {
    char* p = ws + off;
    off += (bytes + 255) & ~(size_t)255;
    return p;
  };
  unsigned short* q_bf = (unsigned short*)alloc((size_t)64 * CS * CHD * 2);  // 32 MB
  unsigned short* k_bf = (unsigned short*)alloc((size_t)64 * CS * CHD * 2);  // 32 MB
  unsigned short* v_bf = (unsigned short*)alloc((size_t)64 * CS * CHD * 2);  // 32 MB: Vt (GEMM1 epi)
  unsigned short* xw = (unsigned short*)alloc((size_t)8192 * CD * 2);        // 32 MB: x_bf, later Y
  unsigned short* wT = (unsigned short*)alloc((size_t)CN3 * CD * 2);         // 24 MB
  float2* tab = (float2*)alloc((size_t)CS * 64 * sizeof(float2));            // 1 MB

  // no memsets: positions = arange(S) -> GEMM1 epilogue writes every k/v element

  k_cvt<<<8192, 256, 0, stream>>>(x, xw, 8192 * CD);
  k_transcvt<<<dim3(CN3 / 32, CD / 32), 256, 0, stream>>>(Wqkv, wT, CD, CN3);
  k_ropetab<<<CS, 64, 0, stream>>>(tab);
  // GEMM1: fused RoPE(q,k)+q-scale epilogue; V written directly as Vt [bh][d][s]
  k_gemm256<0><<<768, 512, 0, stream>>>(xw, wT, nullptr, q_bf, k_bf, v_bf,
                                        positions, tab, 8192, CN3, CD, 24);
  k_transcvt<<<dim3(CD / 32, CD / 32), 256, 0, stream>>>(Wout, wT, CD, CD);
  k_attn<<<1024, 256, 0, stream>>>(q_bf, k_bf, v_bf, xw);
  k_gemm256<1><<<256, 512, 0, stream>>>(xw, wT, out, nullptr, nullptr, nullptr,
                                        nullptr, nullptr, 8192, CD, CD, 8);
}